// Round 3
// baseline (506.458 us; speedup 1.0000x reference)
//
#include <hip/hip_runtime.h>
#include <stdint.h>

typedef int i32x4 __attribute__((ext_vector_type(4)));
typedef unsigned short u16x8 __attribute__((ext_vector_type(8)));

#define N_TOK 2048
#define HID   4096
#define INTER 11008
#define TWOI  22016
#define KS1   64     // HID/64   k-steps for gemm1
#define KS2   172    // INTER/64 k-steps for gemm2

#define GLD16(gp, lp) __builtin_amdgcn_global_load_lds( \
    (const __attribute__((address_space(1))) void*)(gp), \
    (__attribute__((address_space(3))) void*)(lp), 16, 0, 0)
#define BAR() __builtin_amdgcn_s_barrier()
#define WVM(n) asm volatile("s_waitcnt vmcnt(" #n ")" ::: "memory")

__device__ __forceinline__ unsigned short f2bf(float f) {
  uint32_t u = __float_as_uint(f);
  uint32_t r = (u + 0x7fffu + ((u >> 16) & 1u)) >> 16;
  return (unsigned short)r;
}

// ---------------------------------------------------------------------------
// Pack int32 [R][K] -> int8 K-panel layout [K/64][R][64]. Unswizzled: GEMM
// fragment reads consume whole 64B LDS rows -> conflict-free by construction.
// ---------------------------------------------------------------------------
__global__ __launch_bounds__(256) void pack_panel(
    const int* __restrict__ src, uint8_t* __restrict__ dst, int R, int K)
{
  const int u = blockIdx.x * 256 + threadIdx.x;
  const int upk = R * 4;                 // 16B units per k-step
  const int t = u / upk;
  const int rem = u - t * upk;
  const int r = rem >> 2;
  const int c0 = (rem & 3) << 4;
  const int* s = src + (size_t)r * K + t * 64 + c0;
  i32x4 o;
#pragma unroll
  for (int q = 0; q < 4; ++q) {
    i32x4 w = *reinterpret_cast<const i32x4*>(s + q * 4);
    o[q] = (w[0] & 255) | ((w[1] & 255) << 8) | ((w[2] & 255) << 16)
         | ((w[3] & 255) << 24);
  }
  *reinterpret_cast<i32x4*>(dst + (size_t)u * 16) = o;
}

__global__ __launch_bounds__(1024) void zero_mx(float* __restrict__ mx) {
  const int i = blockIdx.x * 1024 + threadIdx.x;
  if (i < N_TOK) mx[i] = 0.0f;
}

// ---------------------------------------------------------------------------
// GEMM1: 256x256 tile, 8 waves (2Mx4N), BK=64B, 4-slot LDS ring, 3-tile
// prefetch depth, counted vmcnt (T3+T4), setprio (T5). B = [gate|up] cols.
// Epilogue: fused silu(gate)*up -> act bf16 [N][I] + per-row atomicMax.
// ---------------------------------------------------------------------------
__global__ __launch_bounds__(512, 2) void gemm1_k(
    const uint8_t* __restrict__ x8p, const uint8_t* __restrict__ wgp,
    const float* __restrict__ xs, const float* __restrict__ wgs,
    unsigned short* __restrict__ act, float* __restrict__ mx)
{
  __shared__ uint8_t sm[131072];         // 4 slots x (A 16KB + B 16KB)
  const int tid = threadIdx.x;
  const int lane = tid & 63, wid = tid >> 6;
  const int wgm = wid >> 2, wgn = wid & 3;
  const int r15 = lane & 15;
  const int khi = (lane >> 4) << 4;

  const int bid = blockIdx.x;
  const int v = (bid & 7) * 86 + (bid >> 3);   // XCD-chunked, bijective
  const int mt = v & 7;
  const int nt = v >> 3;

  const uint8_t* pA  = x8p + (size_t)mt * 256 * 64 + tid * 16;
  const uint8_t* pBg = wgp + (size_t)nt * 128 * 64 + tid * 16;
  const uint8_t* pBu = wgp + ((size_t)INTER + nt * 128) * 64 + tid * 16;

  const int arow = (wgm << 7) + r15;
  const int brow = (wgn << 6) + r15;
  i32x4 acc[8][4] = {};

#define STG1(t, s) do {                                        \
    uint8_t* l = sm + (s) * 32768 + tid * 16;                  \
    const uint8_t* a = pA + (size_t)(t) * 131072;              \
    GLD16(a, l);                                               \
    GLD16(a + 8192, l + 8192);                                 \
    GLD16(pBg + (size_t)(t) * 1409024, l + 16384);             \
    GLD16(pBu + (size_t)(t) * 1409024, l + 24576);             \
  } while (0)

  STG1(0, 0); STG1(1, 1); STG1(2, 2);    // 12 loads in flight
  WVM(8); BAR();                          // tile 0 landed, everywhere

  for (int t = 0; t < KS1; ++t) {
    const int rem = KS1 - 1 - t;
    if (rem >= 3) STG1(t + 3, (t + 3) & 3);   // slot (t-1)&3 free since bar(t-1)
    const uint8_t* b = sm + (t & 3) * 32768;
    i32x4 bv[4], av[8];
#pragma unroll
    for (int n = 0; n < 4; ++n)
      bv[n] = *reinterpret_cast<const i32x4*>(
          b + 16384 + (brow + n * 16) * 64 + khi);
#pragma unroll
    for (int m = 0; m < 8; ++m)
      av[m] = *reinterpret_cast<const i32x4*>(b + (arow + m * 16) * 64 + khi);
    __builtin_amdgcn_s_setprio(1);
#pragma unroll
    for (int m = 0; m < 8; ++m)
#pragma unroll
      for (int n = 0; n < 4; ++n)
        acc[m][n] = __builtin_amdgcn_mfma_i32_16x16x64_i8(
            av[m], bv[n], acc[m][n], 0, 0, 0);
    __builtin_amdgcn_s_setprio(0);
    if (rem >= 3)      { WVM(8); }   // tile t+1 landed; t+2,t+3 stay in flight
    else if (rem == 2) { WVM(4); }
    else if (rem == 1) { WVM(0); }
    BAR();
  }
#undef STG1

  // ---- fused epilogue: silu(gate)*up + rowmax ----
  float* gs = (float*)sm;                 // [256][128] f32, 2-way swizzled
  const int rq = (lane >> 4) << 2;
  if (wgn < 2) {
#pragma unroll
    for (int m = 0; m < 8; ++m) {
#pragma unroll
      for (int n = 0; n < 4; ++n) {
        const int coll = (wgn << 6) + n * 16 + r15;        // 0..127
        const float wsc = wgs[nt * 128 + coll];
#pragma unroll
        for (int r = 0; r < 4; ++r) {
          const int rowl = (wgm << 7) + m * 16 + rq + r;
          const float g = (float)acc[m][n][r] * xs[mt * 256 + rowl] * wsc;
          gs[rowl * 128 + (coll ^ (((rowl >> 2) & 1) << 4))] = g;
        }
      }
    }
  }
  __syncthreads();
  if (wgn >= 2) {
#pragma unroll
    for (int m = 0; m < 8; ++m) {
      float am[4] = {0.f, 0.f, 0.f, 0.f};
#pragma unroll
      for (int n = 0; n < 4; ++n) {
        const int cu = ((wgn - 2) << 6) + n * 16 + r15;    // 0..127
        const float wsc = wgs[INTER + nt * 128 + cu];
#pragma unroll
        for (int r = 0; r < 4; ++r) {
          const int rowl = (wgm << 7) + m * 16 + rq + r;
          const int grow = mt * 256 + rowl;
          const float uv = (float)acc[m][n][r] * xs[grow] * wsc;
          const float g = gs[rowl * 128 + (cu ^ (((rowl >> 2) & 1) << 4))];
          const float a = g / (1.f + __expf(-g)) * uv;
          act[(size_t)grow * INTER + nt * 128 + cu] = f2bf(a);
          am[r] = fmaxf(am[r], __builtin_fabsf(a));
        }
      }
#pragma unroll
      for (int r = 0; r < 4; ++r) {
#pragma unroll
        for (int off = 1; off < 16; off <<= 1)
          am[r] = fmaxf(am[r], __shfl_xor(am[r], off, 64));
      }
      if (r15 == 0) {
#pragma unroll
        for (int r = 0; r < 4; ++r)
          atomicMax((int*)&mx[mt * 256 + (wgm << 7) + m * 16 + rq + r],
                    __float_as_int(am[r]));
      }
    }
  }
}

// ---------------------------------------------------------------------------
// quant: q2 = clip(rint(act * 127/mx)); writes int8 K-panel [I/64][N][64].
// ---------------------------------------------------------------------------
__global__ __launch_bounds__(256) void quant_k(
    const unsigned short* __restrict__ act, const float* __restrict__ mx,
    uint8_t* __restrict__ q2p)
{
  const int u = blockIdx.x * 256 + threadIdx.x;
  const int t = u >> 13;                 // / (2048*4)
  const int rem = u & 8191;
  const int r = rem >> 2;
  const int c0 = (rem & 3) << 4;
  const unsigned short* ap = act + (size_t)r * INTER + t * 64 + c0;
  const float inv = 127.0f / fmaxf(mx[r], 1e-30f);
  u16x8 a0 = *reinterpret_cast<const u16x8*>(ap);
  u16x8 a1 = *reinterpret_cast<const u16x8*>(ap + 8);
  i32x4 o;
#pragma unroll
  for (int q = 0; q < 4; ++q) {
    uint32_t d = 0;
#pragma unroll
    for (int b = 0; b < 4; ++b) {
      const int j = q * 4 + b;
      uint32_t aB = (j < 8) ? a0[j] : a1[j - 8];
      float af = __uint_as_float(aB << 16);
      float rr = rintf(af * inv);
      rr = fminf(fmaxf(rr, -127.f), 127.f);
      d |= ((uint32_t)((int)rr & 255)) << (8 * b);
    }
    o[q] = (int)d;
  }
  *reinterpret_cast<i32x4*>(q2p + (size_t)u * 16) = o;
}

// ---------------------------------------------------------------------------
// GEMM2: 128x256 tile, 8 waves (2Mx4N), BK=64B, 4-slot ring, counted vmcnt.
// out[row][col] = acc * (mx[row]/127) * wds[col], f32.
// ---------------------------------------------------------------------------
__global__ __launch_bounds__(512, 2) void gemm2_k(
    const uint8_t* __restrict__ q2p, const uint8_t* __restrict__ wdp,
    const float* __restrict__ mx, const float* __restrict__ wds,
    float* __restrict__ out)
{
  __shared__ uint8_t sm[98304];          // 4 slots x (A 8KB + B 16KB)
  const int tid = threadIdx.x;
  const int lane = tid & 63, wid = tid >> 6;
  const int wgm = wid >> 2, wgn = wid & 3;
  const int r15 = lane & 15;
  const int khi = (lane >> 4) << 4;

  const int bid = blockIdx.x;
  const int v = (bid & 7) * 32 + (bid >> 3);   // XCD-chunked, bijective
  const int nt = v >> 4, mt = v & 15;

  const uint8_t* pA = q2p + (size_t)mt * 128 * 64 + tid * 16;
  const uint8_t* pB = wdp + (size_t)nt * 256 * 64 + tid * 16;

  const int arow = (wgm << 6) + r15;
  const int brow = (wgn << 6) + r15;
  i32x4 acc[4][4] = {};

#define STG2(t, s) do {                                        \
    uint8_t* l = sm + (s) * 24576 + tid * 16;                  \
    GLD16(pA + (size_t)(t) * 131072, l);                       \
    const uint8_t* bb = pB + (size_t)(t) * 262144;             \
    GLD16(bb, l + 8192);                                       \
    GLD16(bb + 8192, l + 16384);                               \
  } while (0)

  STG2(0, 0); STG2(1, 1); STG2(2, 2);    // 9 loads in flight
  WVM(6); BAR();

  for (int t = 0; t < KS2; ++t) {
    const int rem = KS2 - 1 - t;
    if (rem >= 3) STG2(t + 3, (t + 3) & 3);
    const uint8_t* b = sm + (t & 3) * 24576;
    i32x4 bv[4], av[4];
#pragma unroll
    for (int n = 0; n < 4; ++n)
      bv[n] = *reinterpret_cast<const i32x4*>(
          b + 8192 + (brow + n * 16) * 64 + khi);
#pragma unroll
    for (int m = 0; m < 4; ++m)
      av[m] = *reinterpret_cast<const i32x4*>(b + (arow + m * 16) * 64 + khi);
    __builtin_amdgcn_s_setprio(1);
#pragma unroll
    for (int m = 0; m < 4; ++m)
#pragma unroll
      for (int n = 0; n < 4; ++n)
        acc[m][n] = __builtin_amdgcn_mfma_i32_16x16x64_i8(
            av[m], bv[n], acc[m][n], 0, 0, 0);
    __builtin_amdgcn_s_setprio(0);
    if (rem >= 3)      { WVM(6); }
    else if (rem == 2) { WVM(3); }
    else if (rem == 1) { WVM(0); }
    BAR();
  }
#undef STG2

  const int rq = (lane >> 4) << 2;
#pragma unroll
  for (int m = 0; m < 4; ++m) {
#pragma unroll
    for (int r = 0; r < 4; ++r) {
      const int rowl = (wgm << 6) + m * 16 + rq + r;
      const int grow = mt * 128 + rowl;
      const float s2 = mx[grow] * (1.0f / 127.0f);
      float* op = out + (size_t)grow * HID + nt * 256 + (wgn << 6) + r15;
      const float* wp = wds + nt * 256 + (wgn << 6) + r15;
#pragma unroll
      for (int n = 0; n < 4; ++n)
        op[n * 16] = (float)acc[m][n][r] * s2 * wp[n * 16];
    }
  }
}

// ---------------------------------------------------------------------------
extern "C" void kernel_launch(void* const* d_in, const int* in_sizes, int n_in,
                              void* d_out, int out_size, void* d_ws, size_t ws_size,
                              hipStream_t stream)
{
  const int*   x_q = (const int*)d_in[0];
  const float* xs  = (const float*)d_in[1];
  const int*   wg  = (const int*)d_in[2];
  const float* wgs = (const float*)d_in[3];
  const int*   wd  = (const int*)d_in[4];
  const float* wds = (const float*)d_in[5];
  float* out = (float*)d_out;

  uint8_t* ws = (uint8_t*)d_ws;
  uint8_t* x8p = ws;                                         //   8,388,608
  uint8_t* wgp = x8p + 8388608;                              //  90,177,536
  uint8_t* wdp = wgp + 90177536;                             //  45,088,768
  unsigned short* act = (unsigned short*)(wdp + 45088768);   //  45,088,768
  float* mx = (float*)((uint8_t*)act + 45088768);            //       8,192
  uint8_t* q2p = (uint8_t*)mx + 8192;                        //  22,544,384
  // total ~211.3 MB

  zero_mx<<<2, 1024, 0, stream>>>(mx);
  pack_panel<<<2048, 256, 0, stream>>>(x_q, x8p, N_TOK, HID);
  pack_panel<<<22016, 256, 0, stream>>>(wg, wgp, TWOI, HID);
  pack_panel<<<11008, 256, 0, stream>>>(wd, wdp, HID, INTER);

  gemm1_k<<<688, 512, 0, stream>>>(x8p, wgp, xs, wgs, act, mx);
  quant_k<<<5504, 256, 0, stream>>>(act, mx, q2p);
  gemm2_k<<<256, 512, 0, stream>>>(q2p, wdp, mx, wds, out);
}

// Round 4
// 498.036 us; speedup vs baseline: 1.0169x; 1.0169x over previous
//
#include <hip/hip_runtime.h>
#include <stdint.h>

typedef int i32x4 __attribute__((ext_vector_type(4)));
typedef unsigned short u16x8 __attribute__((ext_vector_type(8)));

#define N_TOK 2048
#define HID   4096
#define INTER 11008
#define TWOI  22016
#define KS1   64     // HID/64   k-steps for gemm1
#define KS2   172    // INTER/64 k-steps for gemm2

#define GLD16(gp, lp) __builtin_amdgcn_global_load_lds( \
    (const __attribute__((address_space(1))) void*)(gp), \
    (__attribute__((address_space(3))) void*)(lp), 16, 0, 0)
#define BAR() __builtin_amdgcn_s_barrier()
#define WVM(n) asm volatile("s_waitcnt vmcnt(" #n ")" ::: "memory")

__device__ __forceinline__ unsigned short f2bf(float f) {
  uint32_t u = __float_as_uint(f);
  uint32_t r = (u + 0x7fffu + ((u >> 16) & 1u)) >> 16;
  return (unsigned short)r;
}

// ---------------------------------------------------------------------------
// Pack int32 [R][K] -> int8 K-panel layout [K/64][R][64], with the four 16B
// units of each 64B row permuted q' = q ^ (row&3) (source-side). GEMM stages
// panels linearly into LDS; fragment reads at slot ((lane>>4)^(r15&3)) then
// land 2 lanes/bank = conflict-free (T2, rule-21 both-sides discipline).
// ---------------------------------------------------------------------------
__global__ __launch_bounds__(256) void pack_panel(
    const int* __restrict__ src, uint8_t* __restrict__ dst, int R, int K)
{
  const int u = blockIdx.x * 256 + threadIdx.x;
  const int upk = R * 4;                 // 16B units per k-step
  const int t = u / upk;
  const int rem = u - t * upk;
  const int r = rem >> 2;
  const int c0 = ((rem & 3) ^ (r & 3)) << 4;   // permuted source unit
  const int* s = src + (size_t)r * K + t * 64 + c0;
  i32x4 o;
#pragma unroll
  for (int q = 0; q < 4; ++q) {
    i32x4 w = *reinterpret_cast<const i32x4*>(s + q * 4);
    o[q] = (w[0] & 255) | ((w[1] & 255) << 8) | ((w[2] & 255) << 16)
         | ((w[3] & 255) << 24);
  }
  *reinterpret_cast<i32x4*>(dst + (size_t)u * 16) = o;
}

__global__ __launch_bounds__(1024) void zero_mx(float* __restrict__ mx) {
  const int i = blockIdx.x * 1024 + threadIdx.x;
  if (i < N_TOK) mx[i] = 0.0f;
}

// ---------------------------------------------------------------------------
// GEMM1: 256x256 tile, 8 waves (2Mx4N), BK=64B, 4-slot LDS ring, 3-tile
// prefetch depth, counted vmcnt (T3+T4), setprio (T5). B = [gate|up] cols.
// Epilogue: fused silu(gate)*up -> act bf16 [N][I] + per-row atomicMax.
// ---------------------------------------------------------------------------
__global__ __launch_bounds__(512, 2) void gemm1_k(
    const uint8_t* __restrict__ x8p, const uint8_t* __restrict__ wgp,
    const float* __restrict__ xs, const float* __restrict__ wgs,
    unsigned short* __restrict__ act, float* __restrict__ mx)
{
  __shared__ uint8_t sm[131072];         // 4 slots x (A 16KB + B 16KB)
  const int tid = threadIdx.x;
  const int lane = tid & 63, wid = tid >> 6;
  const int wgm = wid >> 2, wgn = wid & 3;
  const int r15 = lane & 15;
  const int slotC = (((lane >> 4) ^ (r15 & 3)) << 4);  // de-permuting slot

  const int bid = blockIdx.x;
  const int v = (bid & 7) * 86 + (bid >> 3);   // XCD-chunked, bijective
  const int mt = v & 7;
  const int nt = v >> 3;

  const uint8_t* pA  = x8p + (size_t)mt * 256 * 64 + tid * 16;
  const uint8_t* pBg = wgp + (size_t)nt * 128 * 64 + tid * 16;
  const uint8_t* pBu = wgp + ((size_t)INTER + nt * 128) * 64 + tid * 16;

  const int arow = (wgm << 7) + r15;
  const int brow = (wgn << 6) + r15;
  i32x4 acc[8][4] = {};

#define STG1(t, s) do {                                        \
    uint8_t* l = sm + (s) * 32768 + tid * 16;                  \
    const uint8_t* a = pA + (size_t)(t) * 131072;              \
    GLD16(a, l);                                               \
    GLD16(a + 8192, l + 8192);                                 \
    GLD16(pBg + (size_t)(t) * 1409024, l + 16384);             \
    GLD16(pBu + (size_t)(t) * 1409024, l + 24576);             \
  } while (0)

  STG1(0, 0); STG1(1, 1); STG1(2, 2);    // 12 loads in flight
  WVM(8); BAR();                          // tile 0 landed, everywhere

  for (int t = 0; t < KS1; ++t) {
    const int rem = KS1 - 1 - t;
    if (rem >= 3) STG1(t + 3, (t + 3) & 3);   // slot (t-1)&3 free since bar(t-1)
    const uint8_t* b = sm + (t & 3) * 32768;
    i32x4 bv[4], av[8];
#pragma unroll
    for (int n = 0; n < 4; ++n)
      bv[n] = *reinterpret_cast<const i32x4*>(
          b + 16384 + (brow + n * 16) * 64 + slotC);
#pragma unroll
    for (int m = 0; m < 8; ++m)
      av[m] = *reinterpret_cast<const i32x4*>(b + (arow + m * 16) * 64 + slotC);
    __builtin_amdgcn_s_setprio(1);
#pragma unroll
    for (int m = 0; m < 8; ++m)
#pragma unroll
      for (int n = 0; n < 4; ++n)
        acc[m][n] = __builtin_amdgcn_mfma_i32_16x16x64_i8(
            av[m], bv[n], acc[m][n], 0, 0, 0);
    __builtin_amdgcn_s_setprio(0);
    if (rem >= 3)      { WVM(8); }   // tile t+1 landed; t+2,t+3 stay in flight
    else if (rem == 2) { WVM(4); }
    else if (rem == 1) { WVM(0); }
    BAR();
  }
#undef STG1

  // ---- fused epilogue: silu(gate)*up + rowmax ----
  float* gs = (float*)sm;                 // [256][128] f32, 2-way swizzled
  const int rq = (lane >> 4) << 2;
  if (wgn < 2) {
#pragma unroll
    for (int m = 0; m < 8; ++m) {
#pragma unroll
      for (int n = 0; n < 4; ++n) {
        const int coll = (wgn << 6) + n * 16 + r15;        // 0..127
        const float wsc = wgs[nt * 128 + coll];
#pragma unroll
        for (int r = 0; r < 4; ++r) {
          const int rowl = (wgm << 7) + m * 16 + rq + r;
          const float g = (float)acc[m][n][r] * xs[mt * 256 + rowl] * wsc;
          gs[rowl * 128 + (coll ^ (((rowl >> 2) & 1) << 4))] = g;
        }
      }
    }
  }
  __syncthreads();
  if (wgn >= 2) {
#pragma unroll
    for (int m = 0; m < 8; ++m) {
      float am[4] = {0.f, 0.f, 0.f, 0.f};
#pragma unroll
      for (int n = 0; n < 4; ++n) {
        const int cu = ((wgn - 2) << 6) + n * 16 + r15;    // 0..127
        const float wsc = wgs[INTER + nt * 128 + cu];
#pragma unroll
        for (int r = 0; r < 4; ++r) {
          const int rowl = (wgm << 7) + m * 16 + rq + r;
          const int grow = mt * 256 + rowl;
          const float uv = (float)acc[m][n][r] * xs[grow] * wsc;
          const float g = gs[rowl * 128 + (cu ^ (((rowl >> 2) & 1) << 4))];
          const float a = g / (1.f + __expf(-g)) * uv;
          act[(size_t)grow * INTER + nt * 128 + cu] = f2bf(a);
          am[r] = fmaxf(am[r], __builtin_fabsf(a));
        }
      }
#pragma unroll
      for (int r = 0; r < 4; ++r) {
#pragma unroll
        for (int off = 1; off < 16; off <<= 1)
          am[r] = fmaxf(am[r], __shfl_xor(am[r], off, 64));
      }
      if (r15 == 0) {
#pragma unroll
        for (int r = 0; r < 4; ++r)
          atomicMax((int*)&mx[mt * 256 + (wgm << 7) + m * 16 + rq + r],
                    __float_as_int(am[r]));
      }
    }
  }
}

// ---------------------------------------------------------------------------
// quant: q2 = clip(rint(act * 127/mx)); writes int8 K-panel [I/64][N][64]
// with the same per-row unit permutation as pack_panel.
// ---------------------------------------------------------------------------
__global__ __launch_bounds__(256) void quant_k(
    const unsigned short* __restrict__ act, const float* __restrict__ mx,
    uint8_t* __restrict__ q2p)
{
  const int u = blockIdx.x * 256 + threadIdx.x;
  const int t = u >> 13;                 // / (2048*4)
  const int rem = u & 8191;
  const int r = rem >> 2;
  const int c0 = ((rem & 3) ^ (r & 3)) << 4;   // permuted source unit
  const unsigned short* ap = act + (size_t)r * INTER + t * 64 + c0;
  const float inv = 127.0f / fmaxf(mx[r], 1e-30f);
  u16x8 a0 = *reinterpret_cast<const u16x8*>(ap);
  u16x8 a1 = *reinterpret_cast<const u16x8*>(ap + 8);
  i32x4 o;
#pragma unroll
  for (int q = 0; q < 4; ++q) {
    uint32_t d = 0;
#pragma unroll
    for (int b = 0; b < 4; ++b) {
      const int j = q * 4 + b;
      uint32_t aB = (j < 8) ? a0[j] : a1[j - 8];
      float af = __uint_as_float(aB << 16);
      float rr = rintf(af * inv);
      rr = fminf(fmaxf(rr, -127.f), 127.f);
      d |= ((uint32_t)((int)rr & 255)) << (8 * b);
    }
    o[q] = (int)d;
  }
  *reinterpret_cast<i32x4*>(q2p + (size_t)u * 16) = o;
}

// ---------------------------------------------------------------------------
// GEMM2: 128x256 tile, 8 waves (2Mx4N), BK=64B, 4-slot ring, counted vmcnt.
// out[row][col] = acc * (mx[row]/127) * wds[col], f32.
// ---------------------------------------------------------------------------
__global__ __launch_bounds__(512, 2) void gemm2_k(
    const uint8_t* __restrict__ q2p, const uint8_t* __restrict__ wdp,
    const float* __restrict__ mx, const float* __restrict__ wds,
    float* __restrict__ out)
{
  __shared__ uint8_t sm[98304];          // 4 slots x (A 8KB + B 16KB)
  const int tid = threadIdx.x;
  const int lane = tid & 63, wid = tid >> 6;
  const int wgm = wid >> 2, wgn = wid & 3;
  const int r15 = lane & 15;
  const int slotC = (((lane >> 4) ^ (r15 & 3)) << 4);

  const int bid = blockIdx.x;
  const int v = (bid & 7) * 32 + (bid >> 3);   // XCD-chunked, bijective
  const int nt = v >> 4, mt = v & 15;

  const uint8_t* pA = q2p + (size_t)mt * 128 * 64 + tid * 16;
  const uint8_t* pB = wdp + (size_t)nt * 256 * 64 + tid * 16;

  const int arow = (wgm << 6) + r15;
  const int brow = (wgn << 6) + r15;
  i32x4 acc[4][4] = {};

#define STG2(t, s) do {                                        \
    uint8_t* l = sm + (s) * 24576 + tid * 16;                  \
    GLD16(pA + (size_t)(t) * 131072, l);                       \
    const uint8_t* bb = pB + (size_t)(t) * 262144;             \
    GLD16(bb, l + 8192);                                       \
    GLD16(bb + 8192, l + 16384);                               \
  } while (0)

  STG2(0, 0); STG2(1, 1); STG2(2, 2);    // 9 loads in flight
  WVM(6); BAR();

  for (int t = 0; t < KS2; ++t) {
    const int rem = KS2 - 1 - t;
    if (rem >= 3) STG2(t + 3, (t + 3) & 3);
    const uint8_t* b = sm + (t & 3) * 24576;
    i32x4 bv[4], av[4];
#pragma unroll
    for (int n = 0; n < 4; ++n)
      bv[n] = *reinterpret_cast<const i32x4*>(
          b + 8192 + (brow + n * 16) * 64 + slotC);
#pragma unroll
    for (int m = 0; m < 4; ++m)
      av[m] = *reinterpret_cast<const i32x4*>(b + (arow + m * 16) * 64 + slotC);
    __builtin_amdgcn_s_setprio(1);
#pragma unroll
    for (int m = 0; m < 4; ++m)
#pragma unroll
      for (int n = 0; n < 4; ++n)
        acc[m][n] = __builtin_amdgcn_mfma_i32_16x16x64_i8(
            av[m], bv[n], acc[m][n], 0, 0, 0);
    __builtin_amdgcn_s_setprio(0);
    if (rem >= 3)      { WVM(6); }
    else if (rem == 2) { WVM(3); }
    else if (rem == 1) { WVM(0); }
    BAR();
  }
#undef STG2

  const int rq = (lane >> 4) << 2;
#pragma unroll
  for (int m = 0; m < 4; ++m) {
#pragma unroll
    for (int r = 0; r < 4; ++r) {
      const int rowl = (wgm << 6) + m * 16 + rq + r;
      const int grow = mt * 128 + rowl;
      const float s2 = mx[grow] * (1.0f / 127.0f);
      float* op = out + (size_t)grow * HID + nt * 256 + (wgn << 6) + r15;
      const float* wp = wds + nt * 256 + (wgn << 6) + r15;
#pragma unroll
      for (int n = 0; n < 4; ++n)
        op[n * 16] = (float)acc[m][n][r] * s2 * wp[n * 16];
    }
  }
}

// ---------------------------------------------------------------------------
extern "C" void kernel_launch(void* const* d_in, const int* in_sizes, int n_in,
                              void* d_out, int out_size, void* d_ws, size_t ws_size,
                              hipStream_t stream)
{
  const int*   x_q = (const int*)d_in[0];
  const float* xs  = (const float*)d_in[1];
  const int*   wg  = (const int*)d_in[2];
  const float* wgs = (const float*)d_in[3];
  const int*   wd  = (const int*)d_in[4];
  const float* wds = (const float*)d_in[5];
  float* out = (float*)d_out;

  uint8_t* ws = (uint8_t*)d_ws;
  uint8_t* x8p = ws;                                         //   8,388,608
  uint8_t* wgp = x8p + 8388608;                              //  90,177,536
  uint8_t* wdp = wgp + 90177536;                             //  45,088,768
  unsigned short* act = (unsigned short*)(wdp + 45088768);   //  45,088,768
  float* mx = (float*)((uint8_t*)act + 45088768);            //       8,192
  uint8_t* q2p = (uint8_t*)mx + 8192;                        //  22,544,384
  // total ~211.3 MB

  zero_mx<<<2, 1024, 0, stream>>>(mx);
  pack_panel<<<2048, 256, 0, stream>>>(x_q, x8p, N_TOK, HID);
  pack_panel<<<22016, 256, 0, stream>>>(wg, wgp, TWOI, HID);
  pack_panel<<<11008, 256, 0, stream>>>(wd, wdp, HID, INTER);

  gemm1_k<<<688, 512, 0, stream>>>(x8p, wgp, xs, wgs, act, mx);
  quant_k<<<5504, 256, 0, stream>>>(act, mx, q2p);
  gemm2_k<<<256, 512, 0, stream>>>(q2p, wdp, mx, wds, out);
}

// Round 6
// 477.813 us; speedup vs baseline: 1.0599x; 1.0423x over previous
//
#include <hip/hip_runtime.h>
#include <stdint.h>

typedef int i32x4 __attribute__((ext_vector_type(4)));
typedef unsigned short u16x8 __attribute__((ext_vector_type(8)));

#define N_TOK 2048
#define HID   4096
#define INTER 11008
#define TWOI  22016
#define KS1   64     // HID/64   k-steps for gemm1
#define KS2   172    // INTER/64 k-steps for gemm2

#define GLD16(gp, lp) __builtin_amdgcn_global_load_lds( \
    (const __attribute__((address_space(1))) void*)(gp), \
    (__attribute__((address_space(3))) void*)(lp), 16, 0, 0)
#define BAR() __builtin_amdgcn_s_barrier()
#define WVM(n) asm volatile("s_waitcnt vmcnt(" #n ")" ::: "memory")
// rule #18: lgkmcnt asm must be followed by sched_barrier(0) so MFMAs
// can't be hoisted above the wait.
#define LGKM0() do { asm volatile("s_waitcnt lgkmcnt(0)" ::: "memory"); \
                     __builtin_amdgcn_sched_barrier(0); } while (0)

__device__ __forceinline__ unsigned short f2bf(float f) {
  uint32_t u = __float_as_uint(f);
  uint32_t r = (u + 0x7fffu + ((u >> 16) & 1u)) >> 16;
  return (unsigned short)r;
}

// ---------------------------------------------------------------------------
// Pack int32 [R][K] -> int8 K-panel layout [K/64][R][64], four 16B units per
// row permuted q' = q ^ (row&3) (source-side); GEMMs stage linearly and read
// at slot ((lane>>4)^(r15&3)) -> de-permuted, banks spread.
// ---------------------------------------------------------------------------
__global__ __launch_bounds__(256) void pack_panel(
    const int* __restrict__ src, uint8_t* __restrict__ dst, int R, int K)
{
  const int u = blockIdx.x * 256 + threadIdx.x;
  const int upk = R * 4;                 // 16B units per k-step
  const int t = u / upk;
  const int rem = u - t * upk;
  const int r = rem >> 2;
  const int c0 = ((rem & 3) ^ (r & 3)) << 4;   // permuted source unit
  const int* s = src + (size_t)r * K + t * 64 + c0;
  i32x4 o;
#pragma unroll
  for (int q = 0; q < 4; ++q) {
    i32x4 w = *reinterpret_cast<const i32x4*>(s + q * 4);
    o[q] = (w[0] & 255) | ((w[1] & 255) << 8) | ((w[2] & 255) << 16)
         | ((w[3] & 255) << 24);
  }
  *reinterpret_cast<i32x4*>(dst + (size_t)u * 16) = o;
}

__global__ __launch_bounds__(1024) void zero_mx(float* __restrict__ mx) {
  const int i = blockIdx.x * 1024 + threadIdx.x;
  if (i < N_TOK) mx[i] = 0.0f;
}

// ---------------------------------------------------------------------------
// GEMM1: 256x256 tile, 8 waves (2Mx4N), BK=64B, 4-slot LDS ring, distance-3
// prefetch, counted vmcnt, and a 2-phase interleaved K-step (T3):
//   phase A: ds(bv4+avlo4) + stage B-halves | bar | lgkm0 | 16 MFMA
//   phase B: ds(avhi4)     + stage A-halves | vmcnt | bar | lgkm0 | 16 MFMA
// WAR safety: gld of tile t+3 writes slot (t-1)&3; that slot's region was
// last read >= 1 barrier + 1 MFMA cluster earlier, and the gld LDS-write
// lands >= L2 latency after issue.
// ---------------------------------------------------------------------------
__global__ __launch_bounds__(512, 2) void gemm1_k(
    const uint8_t* __restrict__ x8p, const uint8_t* __restrict__ wgp,
    const float* __restrict__ xs, const float* __restrict__ wgs,
    unsigned short* __restrict__ act, float* __restrict__ mx)
{
  __shared__ uint8_t sm[131072];         // 4 slots x (A 16KB + B 16KB)
  const int tid = threadIdx.x;
  const int lane = tid & 63, wid = tid >> 6;
  const int wgm = wid >> 2, wgn = wid & 3;
  const int r15 = lane & 15;
  const int slotC = (((lane >> 4) ^ (r15 & 3)) << 4);  // de-permuting slot

  const int bid = blockIdx.x;
  const int v = (bid & 7) * 86 + (bid >> 3);   // XCD-chunked, bijective
  const int mt = v & 7;
  const int nt = v >> 3;

  const uint8_t* pA  = x8p + (size_t)mt * 256 * 64 + tid * 16;
  const uint8_t* pBg = wgp + (size_t)nt * 128 * 64 + tid * 16;
  const uint8_t* pBu = wgp + ((size_t)INTER + nt * 128) * 64 + tid * 16;

  const int arow = (wgm << 7) + r15;
  const int brow = (wgn << 6) + r15;
  i32x4 acc[8][4] = {};

#define STG1(t, s) do {                                        \
    uint8_t* l = sm + (s) * 32768 + tid * 16;                  \
    const uint8_t* a = pA + (size_t)(t) * 131072;              \
    GLD16(a, l);                                               \
    GLD16(a + 8192, l + 8192);                                 \
    GLD16(pBg + (size_t)(t) * 1409024, l + 16384);             \
    GLD16(pBu + (size_t)(t) * 1409024, l + 24576);             \
  } while (0)

  STG1(0, 0); STG1(1, 1); STG1(2, 2);    // 12 loads in flight
  WVM(8); BAR();                          // tile 0 landed, everywhere

  for (int t = 0; t < KS1; ++t) {
    const int rem = KS1 - 1 - t;
    const uint8_t* b = sm + (t & 3) * 32768;
    uint8_t* lnx = sm + ((t + 3) & 3) * 32768 + tid * 16;
    // ---------- phase A ----------
    i32x4 bv[4], av[4];
#pragma unroll
    for (int n = 0; n < 4; ++n)
      bv[n] = *reinterpret_cast<const i32x4*>(
          b + 16384 + (brow + n * 16) * 64 + slotC);
#pragma unroll
    for (int m = 0; m < 4; ++m)
      av[m] = *reinterpret_cast<const i32x4*>(b + (arow + m * 16) * 64 + slotC);
    if (rem >= 3) {
      GLD16(pBg + (size_t)(t + 3) * 1409024, lnx + 16384);
      GLD16(pBu + (size_t)(t + 3) * 1409024, lnx + 24576);
    }
    BAR();
    LGKM0();
    __builtin_amdgcn_s_setprio(1);
#pragma unroll
    for (int m = 0; m < 4; ++m)
#pragma unroll
      for (int n = 0; n < 4; ++n)
        acc[m][n] = __builtin_amdgcn_mfma_i32_16x16x64_i8(
            av[m], bv[n], acc[m][n], 0, 0, 0);
    __builtin_amdgcn_s_setprio(0);
    // ---------- phase B ----------
#pragma unroll
    for (int m = 0; m < 4; ++m)
      av[m] = *reinterpret_cast<const i32x4*>(
          b + (arow + (m + 4) * 16) * 64 + slotC);
    if (rem >= 3) {
      const uint8_t* a = pA + (size_t)(t + 3) * 131072;
      GLD16(a, lnx);
      GLD16(a + 8192, lnx + 8192);
      WVM(8);                      // retire tile t+1 (read next step)
    } else if (rem == 2) { WVM(4); }
    else if (rem == 1)   { WVM(0); }
    BAR();
    LGKM0();
    __builtin_amdgcn_s_setprio(1);
#pragma unroll
    for (int m = 0; m < 4; ++m)
#pragma unroll
      for (int n = 0; n < 4; ++n)
        acc[m + 4][n] = __builtin_amdgcn_mfma_i32_16x16x64_i8(
            av[m], bv[n], acc[m + 4][n], 0, 0, 0);
    __builtin_amdgcn_s_setprio(0);
  }
#undef STG1

  __syncthreads();
  // ---- fused epilogue: silu(gate)*up + rowmax ----
  float* gs = (float*)sm;                 // [256][128] f32, 2-way swizzled
  const int rq = (lane >> 4) << 2;
  if (wgn < 2) {
#pragma unroll
    for (int m = 0; m < 8; ++m) {
#pragma unroll
      for (int n = 0; n < 4; ++n) {
        const int coll = (wgn << 6) + n * 16 + r15;        // 0..127
        const float wsc = wgs[nt * 128 + coll];
#pragma unroll
        for (int r = 0; r < 4; ++r) {
          const int rowl = (wgm << 7) + m * 16 + rq + r;
          const float g = (float)acc[m][n][r] * xs[mt * 256 + rowl] * wsc;
          gs[rowl * 128 + (coll ^ (((rowl >> 2) & 1) << 4))] = g;
        }
      }
    }
  }
  __syncthreads();
  if (wgn >= 2) {
#pragma unroll
    for (int m = 0; m < 8; ++m) {
      float am[4] = {0.f, 0.f, 0.f, 0.f};
#pragma unroll
      for (int n = 0; n < 4; ++n) {
        const int cu = ((wgn - 2) << 6) + n * 16 + r15;    // 0..127
        const float wsc = wgs[INTER + nt * 128 + cu];
#pragma unroll
        for (int r = 0; r < 4; ++r) {
          const int rowl = (wgm << 7) + m * 16 + rq + r;
          const int grow = mt * 256 + rowl;
          const float uv = (float)acc[m][n][r] * xs[grow] * wsc;
          const float g = gs[rowl * 128 + (cu ^ (((rowl >> 2) & 1) << 4))];
          const float a = g / (1.f + __expf(-g)) * uv;
          act[(size_t)grow * INTER + nt * 128 + cu] = f2bf(a);
          am[r] = fmaxf(am[r], __builtin_fabsf(a));
        }
      }
#pragma unroll
      for (int r = 0; r < 4; ++r) {
#pragma unroll
        for (int off = 1; off < 16; off <<= 1)
          am[r] = fmaxf(am[r], __shfl_xor(am[r], off, 64));
      }
      if (r15 == 0) {
#pragma unroll
        for (int r = 0; r < 4; ++r)
          atomicMax((int*)&mx[mt * 256 + (wgm << 7) + m * 16 + rq + r],
                    __float_as_int(am[r]));
      }
    }
  }
}

// ---------------------------------------------------------------------------
// quant: q2 = clip(rint(act * 127/mx)); writes int8 K-panel [I/64][N][64]
// with the same per-row unit permutation as pack_panel.
// ---------------------------------------------------------------------------
__global__ __launch_bounds__(256) void quant_k(
    const unsigned short* __restrict__ act, const float* __restrict__ mx,
    uint8_t* __restrict__ q2p)
{
  const int u = blockIdx.x * 256 + threadIdx.x;
  const int t = u >> 13;                 // / (2048*4)
  const int rem = u & 8191;
  const int r = rem >> 2;
  const int c0 = ((rem & 3) ^ (r & 3)) << 4;   // permuted source unit
  const unsigned short* ap = act + (size_t)r * INTER + t * 64 + c0;
  const float inv = 127.0f / fmaxf(mx[r], 1e-30f);
  u16x8 a0 = *reinterpret_cast<const u16x8*>(ap);
  u16x8 a1 = *reinterpret_cast<const u16x8*>(ap + 8);
  i32x4 o;
#pragma unroll
  for (int q = 0; q < 4; ++q) {
    uint32_t d = 0;
#pragma unroll
    for (int b = 0; b < 4; ++b) {
      const int j = q * 4 + b;
      uint32_t aB = (j < 8) ? a0[j] : a1[j - 8];
      float af = __uint_as_float(aB << 16);
      float rr = rintf(af * inv);
      rr = fminf(fmaxf(rr, -127.f), 127.f);
      d |= ((uint32_t)((int)rr & 255)) << (8 * b);
    }
    o[q] = (int)d;
  }
  *reinterpret_cast<i32x4*>(q2p + (size_t)u * 16) = o;
}

// ---------------------------------------------------------------------------
// GEMM2: 128x256 tile, 8 waves (2Mx4N), BK=64B, 4-slot ring, counted vmcnt,
// 2-phase interleaved K-step (8+8 MFMA).
// ---------------------------------------------------------------------------
__global__ __launch_bounds__(512, 2) void gemm2_k(
    const uint8_t* __restrict__ q2p, const uint8_t* __restrict__ wdp,
    const float* __restrict__ mx, const float* __restrict__ wds,
    float* __restrict__ out)
{
  __shared__ uint8_t sm[98304];          // 4 slots x (A 8KB + B 16KB)
  const int tid = threadIdx.x;
  const int lane = tid & 63, wid = tid >> 6;
  const int wgm = wid >> 2, wgn = wid & 3;
  const int r15 = lane & 15;
  const int slotC = (((lane >> 4) ^ (r15 & 3)) << 4);

  const int bid = blockIdx.x;
  const int v = (bid & 7) * 32 + (bid >> 3);   // XCD-chunked, bijective
  const int nt = v >> 4, mt = v & 15;

  const uint8_t* pA = q2p + (size_t)mt * 128 * 64 + tid * 16;
  const uint8_t* pB = wdp + (size_t)nt * 256 * 64 + tid * 16;

  const int arow = (wgm << 6) + r15;
  const int brow = (wgn << 6) + r15;
  i32x4 acc[4][4] = {};

#define STG2(t, s) do {                                        \
    uint8_t* l = sm + (s) * 24576 + tid * 16;                  \
    GLD16(pA + (size_t)(t) * 131072, l);                       \
    const uint8_t* bb = pB + (size_t)(t) * 262144;             \
    GLD16(bb, l + 8192);                                       \
    GLD16(bb + 8192, l + 16384);                               \
  } while (0)

  STG2(0, 0); STG2(1, 1); STG2(2, 2);    // 9 loads in flight
  WVM(6); BAR();

  for (int t = 0; t < KS2; ++t) {
    const int rem = KS2 - 1 - t;
    const uint8_t* b = sm + (t & 3) * 24576;
    uint8_t* lnx = sm + ((t + 3) & 3) * 24576 + tid * 16;
    // ---------- phase A ----------
    i32x4 bv[4], av[2];
#pragma unroll
    for (int n = 0; n < 4; ++n)
      bv[n] = *reinterpret_cast<const i32x4*>(
          b + 8192 + (brow + n * 16) * 64 + slotC);
#pragma unroll
    for (int m = 0; m < 2; ++m)
      av[m] = *reinterpret_cast<const i32x4*>(b + (arow + m * 16) * 64 + slotC);
    if (rem >= 3) {
      const uint8_t* bb = pB + (size_t)(t + 3) * 262144;
      GLD16(bb, lnx + 8192);
      GLD16(bb + 8192, lnx + 16384);
    }
    BAR();
    LGKM0();
    __builtin_amdgcn_s_setprio(1);
#pragma unroll
    for (int m = 0; m < 2; ++m)
#pragma unroll
      for (int n = 0; n < 4; ++n)
        acc[m][n] = __builtin_amdgcn_mfma_i32_16x16x64_i8(
            av[m], bv[n], acc[m][n], 0, 0, 0);
    __builtin_amdgcn_s_setprio(0);
    // ---------- phase B ----------
#pragma unroll
    for (int m = 0; m < 2; ++m)
      av[m] = *reinterpret_cast<const i32x4*>(
          b + (arow + (m + 2) * 16) * 64 + slotC);
    if (rem >= 3) {
      GLD16(pA + (size_t)(t + 3) * 131072, lnx);
      WVM(6);
    } else if (rem == 2) { WVM(3); }
    else if (rem == 1)   { WVM(0); }
    BAR();
    LGKM0();
    __builtin_amdgcn_s_setprio(1);
#pragma unroll
    for (int m = 0; m < 2; ++m)
#pragma unroll
      for (int n = 0; n < 4; ++n)
        acc[m + 2][n] = __builtin_amdgcn_mfma_i32_16x16x64_i8(
            av[m], bv[n], acc[m + 2][n], 0, 0, 0);
    __builtin_amdgcn_s_setprio(0);
  }
#undef STG2

  const int rq = (lane >> 4) << 2;
#pragma unroll
  for (int m = 0; m < 4; ++m) {
#pragma unroll
    for (int r = 0; r < 4; ++r) {
      const int rowl = (wgm << 6) + m * 16 + rq + r;
      const int grow = mt * 128 + rowl;
      const float s2 = mx[grow] * (1.0f / 127.0f);
      float* op = out + (size_t)grow * HID + nt * 256 + (wgn << 6) + r15;
      const float* wp = wds + nt * 256 + (wgn << 6) + r15;
#pragma unroll
      for (int n = 0; n < 4; ++n)
        op[n * 16] = (float)acc[m][n][r] * s2 * wp[n * 16];
    }
  }
}

// ---------------------------------------------------------------------------
extern "C" void kernel_launch(void* const* d_in, const int* in_sizes, int n_in,
                              void* d_out, int out_size, void* d_ws, size_t ws_size,
                              hipStream_t stream)
{
  const int*   x_q = (const int*)d_in[0];
  const float* xs  = (const float*)d_in[1];
  const int*   wg  = (const int*)d_in[2];
  const float* wgs = (const float*)d_in[3];
  const int*   wd  = (const int*)d_in[4];
  const float* wds = (const float*)d_in[5];
  float* out = (float*)d_out;

  uint8_t* ws = (uint8_t*)d_ws;
  uint8_t* x8p = ws;                                         //   8,388,608
  uint8_t* wgp = x8p + 8388608;                              //  90,177,536
  uint8_t* wdp = wgp + 90177536;                             //  45,088,768
  unsigned short* act = (unsigned short*)(wdp + 45088768);   //  45,088,768
  float* mx = (float*)((uint8_t*)act + 45088768);            //       8,192
  uint8_t* q2p = (uint8_t*)mx + 8192;                        //  22,544,384
  // total ~211.3 MB

  zero_mx<<<2, 1024, 0, stream>>>(mx);
  pack_panel<<<2048, 256, 0, stream>>>(x_q, x8p, N_TOK, HID);
  pack_panel<<<22016, 256, 0, stream>>>(wg, wgp, TWOI, HID);
  pack_panel<<<11008, 256, 0, stream>>>(wd, wdp, HID, INTER);

  gemm1_k<<<688, 512, 0, stream>>>(x8p, wgp, xs, wgs, act, mx);
  quant_k<<<5504, 256, 0, stream>>>(act, mx, q2p);
  gemm2_k<<<256, 512, 0, stream>>>(q2p, wdp, mx, wds, out);
}